// Round 3
// baseline (4962.087 us; speedup 1.0000x reference)
//
#include <hip/hip_runtime.h>
#include <cstdint>
#include <cstddef>

#define SEQ   128
#define BB    32
#define EE    1024
#define HH    1024
#define G4    4096
#define VV    32000
#define NROWS 4096   // SEQ*BB

typedef _Float16 h16x8 __attribute__((ext_vector_type(8)));
typedef _Float16 h16x4 __attribute__((ext_vector_type(4)));
typedef float f32x4  __attribute__((ext_vector_type(4)));

__device__ __forceinline__ float sigmf(float x) { return 1.0f / (1.0f + expf(-x)); }

// ---------------- ws layout (bytes) ----------------
#define OFF_FLAGS   0ull
#define OFF_HFRAG   256ull                    // 6 slots * 32768 f16 = 393216 B
#define OFF_EMB     393472ull                 // [4096][1024] f16
#define OFF_X0      8782080ull                // [4096][4096] f16
#define OFF_WIH0    42336512ull               // [4096][1024] f16
#define OFF_WP4     50725120ull               // 256 wg * 65536 f16
#define OFF_WP0     84279552ull               // 256 wg * 16384 f16
#define OFF_EMBW    92668160ull               // [32000][1024] f16
#define OFF_WIN     158204160ull              // [1024][1024] f16
#define OFF_WOUT    160301312ull              // [1024][2048] f16
#define OFF_ENC     164495616ull              // [64][32][1024] f16
#define OFF_H2ALL   168689920ull              // [4096][1024] f16
#define OFF_CONCAT  177078528ull              // [4096][2048] f16
#define OFF_TARGET  193855744ull              // [4096][1024] f16
#define OFF_HT      202244352ull              // [4096][1024] f16
#define WS_NEEDED   210632960ull

// ---------------- f32 -> f16 convert (vectorized, grid-stride) ----------------
__global__ __launch_bounds__(256) void k_conv(const float* __restrict__ s,
                                              _Float16* __restrict__ d, int n4) {
  int i = blockIdx.x * blockDim.x + threadIdx.x;
  int st = gridDim.x * blockDim.x;
  for (; i < n4; i += st) {
    float4 v = ((const float4*)s)[i];
    h16x4 o; o[0] = (_Float16)v.x; o[1] = (_Float16)v.y; o[2] = (_Float16)v.z; o[3] = (_Float16)v.w;
    ((h16x4*)d)[i] = o;
  }
}

// ---------------- embedding gather -> f16 ----------------
__global__ __launch_bounds__(256) void k_gather(const int* __restrict__ tok,
                                                const float* __restrict__ embW,
                                                _Float16* __restrict__ emb) {
  int row = blockIdx.x;                 // row = t*32+b
  int t = tok[row];
  float4 v = ((const float4*)(embW + (size_t)t * EE))[threadIdx.x];
  h16x4 o; o[0] = (_Float16)v.x; o[1] = (_Float16)v.y; o[2] = (_Float16)v.z; o[3] = (_Float16)v.w;
  ((h16x4*)(emb + (size_t)row * EE))[threadIdx.x] = o;
}

// ---------------- pack 4 LDS-resident matrices (Wih1,Whh1,Wih2,Whh2) ----------------
// Wpack4[w][mat][jj][k_lds] = W[layer][row(w,jj)][k_lds ^ ((jj&7)<<3)]  (XOR pre-swizzle)
__global__ __launch_bounds__(256) void k_packw4(const float* __restrict__ Wih,
                                                const float* __restrict__ Whh,
                                                _Float16* __restrict__ out) {
  int i = blockIdx.x * blockDim.x + threadIdx.x;
  int st = gridDim.x * blockDim.x;
  const int total = 256 * 65536;
  for (; i < total; i += st) {
    int w = i >> 16, rem = i & 65535;
    int mat = rem >> 14, jj = (rem >> 10) & 15, k = rem & 1023;
    int layer = 1 + (mat >> 1), isHH = mat & 1;
    int row = ((jj >> 2) << 10) + (w << 2) + (jj & 3);
    int ks = k ^ ((jj & 7) << 3);
    const float* src = (isHH ? Whh : Wih) + (size_t)layer * G4 * 1024 + (size_t)row * 1024 + ks;
    out[i] = (_Float16)(*src);
  }
}

// ---------------- pack Whh0 fragment-linear: [w][ks 0..31][lane 0..63][e 0..7] ----------------
__global__ __launch_bounds__(256) void k_packw0(const float* __restrict__ Whh,
                                                _Float16* __restrict__ out) {
  int i = blockIdx.x * blockDim.x + threadIdx.x;
  int st = gridDim.x * blockDim.x;
  const int total = 256 * 16384;
  for (; i < total; i += st) {
    int w = i >> 14, rem = i & 16383;
    int ks = rem >> 9, lane = (rem >> 3) & 63, e = rem & 7;
    int jj = lane & 15, q = lane >> 4;
    int row = ((jj >> 2) << 10) + (w << 2) + (jj & 3);
    int k = ks * 32 + q * 8 + e;
    out[i] = (_Float16)Whh[(size_t)row * 1024 + k];   // layer 0
  }
}

// ---------------- init: barrier flags + initial h fragments ----------------
// parity init per layer: l0 -> slot[0][1], l1 -> slot[1][0], l2 -> slot[2][1]
__global__ __launch_bounds__(256) void k_init(const float* __restrict__ h0,
                                              _Float16* __restrict__ hfrag,
                                              unsigned* __restrict__ flags) {
  int i = blockIdx.x * blockDim.x + threadIdx.x;
  if (i == 0) { flags[0] = 0u; flags[1] = 0u; }
  if (i >= 3 * BB * HH) return;
  int l = i >> 15, rem = i & 32767;
  int b = rem >> 10, n = rem & 1023;
  int parI = (l == 1) ? 0 : 1;
  int tbb = b >> 4, ks = n >> 5, q = (n >> 3) & 3, e = n & 7;
  int lane2 = (b & 15) | (q << 4);
  hfrag[(size_t)(l * 2 + parI) * 32768 + ((size_t)(tbb * 32 + ks) * 64 + lane2) * 8 + e] =
      (_Float16)h0[i];
}

// ---------------- generic 128x128 BT GEMM (A[M,K] f16, B[N,K] f16) ----------------
// EPI: 0 = f32 + bias1 ; 1 = f16 ; 2 = f16(tanh) ; 3 = f16 + bias1 + bias2
template <int EPI>
__global__ __launch_bounds__(256) void k_gemm(const _Float16* __restrict__ A,
                                              const _Float16* __restrict__ B,
                                              void* __restrict__ C, int M, int N, int K,
                                              const float* __restrict__ bias1,
                                              const float* __restrict__ bias2) {
  __shared__ _Float16 As[2][128 * 32];
  __shared__ _Float16 Bs[2][128 * 32];
  const int ntn = N / 128;
  const int tm = blockIdx.x / ntn, tn = blockIdx.x % ntn;
  const int tid = threadIdx.x, lane = tid & 63;
  const int wv = tid >> 6, wr = wv >> 1, wc = wv & 1;
  f32x4 acc[4][4] = {};

  auto stage = [&](int buf, int k0) {
#pragma unroll
    for (int i = 0; i < 2; ++i) {
      int eo = (i * 256 + tid) * 8;
      int r = eo >> 5, c = eo & 31;
      *(h16x8*)&As[buf][eo] = *(const h16x8*)(A + (size_t)(tm * 128 + r) * K + k0 + c);
      *(h16x8*)&Bs[buf][eo] = *(const h16x8*)(B + (size_t)(tn * 128 + r) * K + k0 + c);
    }
  };
  stage(0, 0);
  __syncthreads();
  const int nk = K / 32;
  for (int kt = 0; kt < nk; ++kt) {
    if (kt + 1 < nk) stage((kt + 1) & 1, (kt + 1) * 32);
    const int buf = kt & 1;
    h16x8 af[4], bfr[4];
#pragma unroll
    for (int mi = 0; mi < 4; ++mi)
      af[mi] = *(const h16x8*)&As[buf][(wr * 64 + mi * 16 + (lane & 15)) * 32 + (lane >> 4) * 8];
#pragma unroll
    for (int ni = 0; ni < 4; ++ni)
      bfr[ni] = *(const h16x8*)&Bs[buf][(wc * 64 + ni * 16 + (lane & 15)) * 32 + (lane >> 4) * 8];
#pragma unroll
    for (int mi = 0; mi < 4; ++mi)
#pragma unroll
      for (int ni = 0; ni < 4; ++ni)
        acc[mi][ni] = __builtin_amdgcn_mfma_f32_16x16x32_f16(af[mi], bfr[ni], acc[mi][ni], 0, 0, 0);
    __syncthreads();
  }
  const int rbase = tm * 128 + wr * 64;
  const int cbase = tn * 128 + wc * 64;
#pragma unroll
  for (int mi = 0; mi < 4; ++mi) {
#pragma unroll
    for (int ni = 0; ni < 4; ++ni) {
#pragma unroll
      for (int r = 0; r < 4; ++r) {
        int mm = rbase + mi * 16 + (lane >> 4) * 4 + r;
        int nn = cbase + ni * 16 + (lane & 15);
        float v = acc[mi][ni][r];
        if (EPI == 0) {
          ((float*)C)[(size_t)mm * N + nn] = v + bias1[nn];
        } else if (EPI == 1) {
          ((_Float16*)C)[(size_t)mm * N + nn] = (_Float16)v;
        } else if (EPI == 2) {
          ((_Float16*)C)[(size_t)mm * N + nn] = (_Float16)tanhf(v);
        } else {
          ((_Float16*)C)[(size_t)mm * N + nn] = (_Float16)(v + bias1[nn] + bias2[nn]);
        }
      }
    }
  }
}

// ---------------- grid barrier (sense-reversing; 256 wgs) ----------------
__device__ __forceinline__ void grid_barrier(unsigned* cnt, unsigned* gen) {
  __syncthreads();
  if (threadIdx.x == 0) {
    __threadfence();  // release
    unsigned g = __hip_atomic_load(gen, __ATOMIC_RELAXED, __HIP_MEMORY_SCOPE_AGENT);
    unsigned a = __hip_atomic_fetch_add(cnt, 1u, __ATOMIC_RELAXED, __HIP_MEMORY_SCOPE_AGENT);
    if (a == 255u) {
      __hip_atomic_store(cnt, 0u, __ATOMIC_RELAXED, __HIP_MEMORY_SCOPE_AGENT);
      __hip_atomic_store(gen, g + 1u, __ATOMIC_RELEASE, __HIP_MEMORY_SCOPE_AGENT);
    } else {
      unsigned gg;
      do {
        __builtin_amdgcn_s_sleep(2);
        gg = __hip_atomic_load(gen, __ATOMIC_RELAXED, __HIP_MEMORY_SCOPE_AGENT);
      } while (gg == g);
    }
    __threadfence();  // acquire
  }
  __syncthreads();
}

// ---------------- persistent pipelined LSTM recurrence ----------------
// 256 wgs x 512 thr. wg w owns hidden units n = 4w..4w+3 (16 gate rows).
// Tick tau: l0 computes h0(tau), l1 computes h1(tau-1), l2 computes h2(tau-2).
// LDS: Wih1|Whh1|Wih2|Whh2 (128KB, XOR-swizzled) + redbuf(18KB) + gbuf(6KB).
// NOTE: launched as a REGULAR kernel (not cooperative — cooperative launches
// break graph capture). Co-residency is structural: 152KB LDS => 1 wg/CU,
// grid 256 == CU count => all wgs resident before the first barrier.
__global__ __launch_bounds__(512) void k_recur(const _Float16* __restrict__ Wp4,
                                               const _Float16* __restrict__ Wp0,
                                               const _Float16* __restrict__ X0bf,
                                               _Float16* __restrict__ hfrag,
                                               _Float16* __restrict__ h2all,
                                               _Float16* __restrict__ concat,
                                               const float* __restrict__ bih,
                                               const float* __restrict__ bhh,
                                               const float* __restrict__ c0p,
                                               unsigned* __restrict__ flags) {
  extern __shared__ char lds[];
  _Float16* ldsW = (_Float16*)lds;                 // 65536 f16
  float* redbuf = (float*)(lds + 131072);          // [3][3][2][256]
  float* gbuf = (float*)(lds + 149504);            // [3][32][16]

  const int w = blockIdx.x;
  const int tid = threadIdx.x, lane = tid & 63, wv = tid >> 6;
  const int tb = wv & 1, kq = wv >> 1;
  const int row = (lane >> 4) * 4, col = lane & 15;

  // preload LDS weights (linear copy; swizzle pre-applied by k_packw4)
  for (int i = 0; i < 16; ++i) {
    int eo = (i * 512 + tid) * 8;
    *(h16x8*)&ldsW[eo] = *(const h16x8*)(Wp4 + (size_t)w * 65536 + eo);
  }
  // Whh0 fragments in registers
  h16x8 w0reg[8];
#pragma unroll
  for (int i = 0; i < 8; ++i)
    w0reg[i] = *(const h16x8*)(Wp0 + (size_t)w * 16384 + ((size_t)(kq * 8 + i) * 64 + lane) * 8);

  // per-thread epilogue state (threads 0..127 own (b, ni))
  const int eb = tid >> 2, eni = tid & 3, en = w * 4 + eni;
  int hoff = 0;
  float c0r = 0.f, c1r = 0.f, c2r = 0.f;
  float b1r[4] = {0, 0, 0, 0}, b2r[4] = {0, 0, 0, 0};
  if (tid < 128) {
    int tbb = eb >> 4, ks2 = en >> 5, q2 = (en >> 3) & 3, e2 = en & 7;
    int lane2 = (eb & 15) | (q2 << 4);
    hoff = ((tbb * 32 + ks2) * 64 + lane2) * 8 + e2;
    c0r = c0p[0 * BB * HH + eb * HH + en];
    c1r = c0p[1 * BB * HH + eb * HH + en];
    c2r = c0p[2 * BB * HH + eb * HH + en];
#pragma unroll
    for (int g = 0; g < 4; ++g) {
      b1r[g] = bih[1 * G4 + g * 1024 + en] + bhh[1 * G4 + g * 1024 + en];
      b2r[g] = bih[2 * G4 + g * 1024 + en] + bhh[2 * G4 + g * 1024 + en];
    }
  }
  __syncthreads();

  for (int tau = 0; tau < 130; ++tau) {
    const int p = tau & 1;
    const _Float16* h0r = hfrag + (size_t)(0 + (1 - p)) * 32768;
    const _Float16* h1r = hfrag + (size_t)(2 + (1 - p)) * 32768;
    const _Float16* h2r = hfrag + (size_t)(4 + (1 - p)) * 32768;

    // A fragments (coalesced 16B/lane); inactive-layer reads feed discarded accs
    h16x8 a0[8], a1[8], a2[8];
#pragma unroll
    for (int i = 0; i < 8; ++i) {
      int ks = kq * 8 + i;
      size_t off = ((size_t)(tb * 32 + ks) * 64 + lane) * 8;
      a0[i] = *(const h16x8*)(h0r + off);
      a1[i] = *(const h16x8*)(h1r + off);
      a2[i] = *(const h16x8*)(h2r + off);
    }
    f32x4 acc0 = {}, acc1 = {}, acc2 = {};
#pragma unroll
    for (int i = 0; i < 8; ++i) {
      int ks = kq * 8 + i;
      int jj = lane & 15, q = lane >> 4;
      int kk = (ks * 32 + q * 8) ^ ((jj & 7) << 3);
      const h16x8 bw1i = *(const h16x8*)&ldsW[0 * 16384 + jj * 1024 + kk];
      const h16x8 bw1h = *(const h16x8*)&ldsW[1 * 16384 + jj * 1024 + kk];
      const h16x8 bw2i = *(const h16x8*)&ldsW[2 * 16384 + jj * 1024 + kk];
      const h16x8 bw2h = *(const h16x8*)&ldsW[3 * 16384 + jj * 1024 + kk];
      acc0 = __builtin_amdgcn_mfma_f32_16x16x32_f16(a0[i], w0reg[i], acc0, 0, 0, 0);
      acc1 = __builtin_amdgcn_mfma_f32_16x16x32_f16(a0[i], bw1i, acc1, 0, 0, 0);
      acc1 = __builtin_amdgcn_mfma_f32_16x16x32_f16(a1[i], bw1h, acc1, 0, 0, 0);
      acc2 = __builtin_amdgcn_mfma_f32_16x16x32_f16(a1[i], bw2i, acc2, 0, 0, 0);
      acc2 = __builtin_amdgcn_mfma_f32_16x16x32_f16(a2[i], bw2h, acc2, 0, 0, 0);
    }
    // cross-wave K reduction
    if (kq >= 1) {
      int s = kq - 1;
#pragma unroll
      for (int r = 0; r < 4; ++r) {
        redbuf[((0 * 3 + s) * 2 + tb) * 256 + (row + r) * 16 + col] = acc0[r];
        redbuf[((1 * 3 + s) * 2 + tb) * 256 + (row + r) * 16 + col] = acc1[r];
        redbuf[((2 * 3 + s) * 2 + tb) * 256 + (row + r) * 16 + col] = acc2[r];
      }
    }
    __syncthreads();
    if (kq == 0) {
#pragma unroll
      for (int r = 0; r < 4; ++r) {
        float v0 = acc0[r], v1 = acc1[r], v2 = acc2[r];
#pragma unroll
        for (int s = 0; s < 3; ++s) {
          v0 += redbuf[((0 * 3 + s) * 2 + tb) * 256 + (row + r) * 16 + col];
          v1 += redbuf[((1 * 3 + s) * 2 + tb) * 256 + (row + r) * 16 + col];
          v2 += redbuf[((2 * 3 + s) * 2 + tb) * 256 + (row + r) * 16 + col];
        }
        gbuf[(0 * 32 + tb * 16 + row + r) * 16 + col] = v0;
        gbuf[(1 * 32 + tb * 16 + row + r) * 16 + col] = v1;
        gbuf[(2 * 32 + tb * 16 + row + r) * 16 + col] = v2;
      }
    }
    __syncthreads();
    // elementwise LSTM epilogue
    if (tid < 128) {
      if (tau < 128) {  // layer 0: X0 already holds x@Wih0^T + b_ih0 + b_hh0
        size_t xb = ((size_t)(tau * BB + eb)) * G4 + en;
        float gi = gbuf[(0 * 32 + eb) * 16 + eni] + (float)X0bf[xb];
        float gf = gbuf[(0 * 32 + eb) * 16 + 4 + eni] + (float)X0bf[xb + 1024];
        float gg = gbuf[(0 * 32 + eb) * 16 + 8 + eni] + (float)X0bf[xb + 2048];
        float go = gbuf[(0 * 32 + eb) * 16 + 12 + eni] + (float)X0bf[xb + 3072];
        c0r = sigmf(gf) * c0r + sigmf(gi) * tanhf(gg);
        float h = sigmf(go) * tanhf(c0r);
        hfrag[(size_t)(0 + p) * 32768 + hoff] = (_Float16)h;
      }
      if (tau >= 1 && tau < 129) {  // layer 1
        float gi = gbuf[(1 * 32 + eb) * 16 + eni] + b1r[0];
        float gf = gbuf[(1 * 32 + eb) * 16 + 4 + eni] + b1r[1];
        float gg = gbuf[(1 * 32 + eb) * 16 + 8 + eni] + b1r[2];
        float go = gbuf[(1 * 32 + eb) * 16 + 12 + eni] + b1r[3];
        c1r = sigmf(gf) * c1r + sigmf(gi) * tanhf(gg);
        float h = sigmf(go) * tanhf(c1r);
        hfrag[(size_t)(2 + p) * 32768 + hoff] = (_Float16)h;
      }
      if (tau >= 2) {  // layer 2
        float gi = gbuf[(2 * 32 + eb) * 16 + eni] + b2r[0];
        float gf = gbuf[(2 * 32 + eb) * 16 + 4 + eni] + b2r[1];
        float gg = gbuf[(2 * 32 + eb) * 16 + 8 + eni] + b2r[2];
        float go = gbuf[(2 * 32 + eb) * 16 + 12 + eni] + b2r[3];
        c2r = sigmf(gf) * c2r + sigmf(gi) * tanhf(gg);
        float h = sigmf(go) * tanhf(c2r);
        _Float16 hb = (_Float16)h;
        hfrag[(size_t)(4 + p) * 32768 + hoff] = hb;
        int t2 = tau - 2;
        h2all[(size_t)(t2 * BB + eb) * HH + en] = hb;
        concat[(size_t)(t2 * BB + eb) * 2048 + 1024 + en] = hb;
      }
    }
    grid_barrier(flags, flags + 1);
  }
}

// ---------------- fused scores+softmax+weighted-context per (t,b) ----------------
__global__ __launch_bounds__(256) void k_attn(const _Float16* __restrict__ target,
                                              const _Float16* __restrict__ encb,
                                              _Float16* __restrict__ concat) {
  __shared__ float sc[64];
  __shared__ float att[64];
  int m = blockIdx.x, b = m & 31;
  int tid = threadIdx.x, lane = tid & 63, wv = tid >> 6;
  const h16x8* tp = (const h16x8*)(target + (size_t)m * EE + lane * 16);
  h16x8 tg0 = tp[0], tg1 = tp[1];
  for (int si = 0; si < 16; ++si) {
    int s = wv * 16 + si;
    const h16x8* ep = (const h16x8*)(encb + ((size_t)s * BB + b) * EE + lane * 16);
    h16x8 e0 = ep[0], e1 = ep[1];
    float a = 0.f;
#pragma unroll
    for (int j = 0; j < 8; ++j) a += (float)e0[j] * (float)tg0[j];
#pragma unroll
    for (int j = 0; j < 8; ++j) a += (float)e1[j] * (float)tg1[j];
#pragma unroll
    for (int off = 32; off >= 1; off >>= 1) a += __shfl_xor(a, off);
    if (lane == 0) sc[s] = a;
  }
  __syncthreads();
  if (wv == 0) {
    float v = sc[lane], mx = v;
#pragma unroll
    for (int off = 32; off >= 1; off >>= 1) mx = fmaxf(mx, __shfl_xor(mx, off));
    float e = expf(v - mx), sm = e;
#pragma unroll
    for (int off = 32; off >= 1; off >>= 1) sm += __shfl_xor(sm, off);
    att[lane] = e / sm;
  }
  __syncthreads();
  int e4 = tid * 4;
  float a0 = 0, a1 = 0, a2 = 0, a3 = 0;
  for (int s = 0; s < 64; ++s) {
    float wgt = att[s];
    h16x4 ev = *(const h16x4*)(encb + ((size_t)s * BB + b) * EE + e4);
    a0 += wgt * (float)ev[0]; a1 += wgt * (float)ev[1];
    a2 += wgt * (float)ev[2]; a3 += wgt * (float)ev[3];
  }
  h16x4 o; o[0] = (_Float16)a0; o[1] = (_Float16)a1; o[2] = (_Float16)a2; o[3] = (_Float16)a3;
  *(h16x4*)(concat + (size_t)m * 2048 + e4) = o;
}

// ---------------- host ----------------
extern "C" void kernel_launch(void* const* d_in, const int* in_sizes, int n_in,
                              void* d_out, int out_size, void* d_ws, size_t ws_size,
                              hipStream_t stream) {
  const int* tokens = (const int*)d_in[0];
  const float* embW = (const float*)d_in[1];
  const float* Wih = (const float*)d_in[2];
  const float* Whh = (const float*)d_in[3];
  const float* bih = (const float*)d_in[4];
  const float* bhh = (const float*)d_in[5];
  const float* Win = (const float*)d_in[6];
  const float* Wout = (const float*)d_in[7];
  const float* finalb = (const float*)d_in[8];
  const float* enc = (const float*)d_in[9];
  const float* h0 = (const float*)d_in[10];
  const float* c0 = (const float*)d_in[11];
  (void)in_sizes; (void)n_in; (void)out_size;
  if (ws_size < WS_NEEDED) return;

  char* ws = (char*)d_ws;
  unsigned* flags = (unsigned*)(ws + OFF_FLAGS);
  _Float16* hfrag = (_Float16*)(ws + OFF_HFRAG);
  _Float16* emb = (_Float16*)(ws + OFF_EMB);
  _Float16* X0bf = (_Float16*)(ws + OFF_X0);
  _Float16* Wih0b = (_Float16*)(ws + OFF_WIH0);
  _Float16* Wp4 = (_Float16*)(ws + OFF_WP4);
  _Float16* Wp0 = (_Float16*)(ws + OFF_WP0);
  _Float16* embWb = (_Float16*)(ws + OFF_EMBW);
  _Float16* Winb = (_Float16*)(ws + OFF_WIN);
  _Float16* Woutb = (_Float16*)(ws + OFF_WOUT);
  _Float16* encb = (_Float16*)(ws + OFF_ENC);
  _Float16* h2all = (_Float16*)(ws + OFF_H2ALL);
  _Float16* concat = (_Float16*)(ws + OFF_CONCAT);
  _Float16* target = (_Float16*)(ws + OFF_TARGET);
  _Float16* ht = (_Float16*)(ws + OFF_HT);

  const unsigned LDSB = 155648;  // 128KB weights + 18KB redbuf + 6KB gbuf
  static int lds_set = 0;
  if (!lds_set) {
    hipFuncSetAttribute((const void*)k_recur, hipFuncAttributeMaxDynamicSharedMemorySize,
                        (int)LDSB);
    lds_set = 1;   // attribute is sticky on the function; setting once is enough
  }

  // prep: converts / packs / init
  k_conv<<<4096, 256, 0, stream>>>(embW, embWb, VV * EE / 4);
  k_conv<<<1024, 256, 0, stream>>>(Wih, Wih0b, G4 * EE / 4);       // layer-0 W_ih
  k_conv<<<512, 256, 0, stream>>>(Win, Winb, EE * EE / 4);
  k_conv<<<512, 256, 0, stream>>>(Wout, Woutb, EE * 2048 / 4);
  k_conv<<<512, 256, 0, stream>>>(enc, encb, 64 * BB * EE / 4);
  k_gather<<<NROWS, 256, 0, stream>>>(tokens, embW, emb);
  k_packw4<<<8192, 256, 0, stream>>>(Wih, Whh, Wp4);
  k_packw0<<<4096, 256, 0, stream>>>(Whh, Wp0);
  k_init<<<384, 256, 0, stream>>>(h0, hfrag, flags);

  // X0 = emb @ Wih0^T + b_ih0 + b_hh0   -> f16 [4096,4096]
  k_gemm<3><<<32 * 32, 256, 0, stream>>>(emb, Wih0b, X0bf, NROWS, G4, EE, bih, bhh);

  // recurrence: REGULAR launch (graph-capturable); co-residency structural
  k_recur<<<256, 512, LDSB, stream>>>(Wp4, Wp0, X0bf, hfrag, h2all, concat,
                                      bih, bhh, c0, flags);

  // attention chain
  k_gemm<1><<<32 * 8, 256, 0, stream>>>(h2all, Winb, target, NROWS, EE, EE, nullptr, nullptr);
  k_attn<<<NROWS, 256, 0, stream>>>(target, encb, concat);
  k_gemm<2><<<32 * 8, 256, 0, stream>>>(concat, Woutb, ht, NROWS, EE, 2048, nullptr, nullptr);

  // logits = ht @ embW^T + final_b  -> f32 d_out
  k_gemm<0><<<32 * 250, 256, 0, stream>>>(ht, embWb, d_out, NROWS, VV, EE, finalb, nullptr);
}

// Round 4
// 2880.758 us; speedup vs baseline: 1.7225x; 1.7225x over previous
//
#include <hip/hip_runtime.h>
#include <cstdint>
#include <cstddef>

#define SEQ   128
#define BB    32
#define EE    1024
#define HH    1024
#define G4    4096
#define VV    32000
#define NROWS 4096   // SEQ*BB

typedef _Float16 h16x8 __attribute__((ext_vector_type(8)));
typedef _Float16 h16x4 __attribute__((ext_vector_type(4)));
typedef float f32x4  __attribute__((ext_vector_type(4)));

#define AS_G(p) ((const __attribute__((address_space(1))) void*)(p))
#define AS_L(p) ((__attribute__((address_space(3))) void*)(p))

__device__ __forceinline__ float sigmf(float x) { return 1.0f / (1.0f + expf(-x)); }

// ---------------- ws layout (bytes) ----------------
// sync region: gen @0 (256B pad), arrive[256] @256 stride 128B (32KB)
#define OFF_SYNC    0ull
#define OFF_HFRAG   33024ull                  // 6 slots * 32768 f16 = 393216 B
#define OFF_EMB     426240ull                 // [4096][1024] f16
#define OFF_X0      8814848ull                // [4096][4096] f16
#define OFF_WIH0    42369280ull               // [4096][1024] f16
#define OFF_WP4     50757888ull               // 256 wg * 65536 f16
#define OFF_WP0     84312320ull               // 256 wg * 16384 f16
#define OFF_EMBW    92700928ull               // [32000][1024] f16
#define OFF_WIN     158236928ull              // [1024][1024] f16
#define OFF_WOUT    160334080ull              // [1024][2048] f16
#define OFF_ENC     164528384ull              // [64][32][1024] f16
#define OFF_H2ALL   168722688ull              // [4096][1024] f16
#define OFF_CONCAT  177111296ull              // [4096][2048] f16
#define OFF_TARGET  193888512ull              // [4096][1024] f16
#define OFF_HT      202277120ull              // [4096][1024] f16
#define WS_NEEDED   210665728ull

// ---------------- f32 -> f16 convert (vectorized, grid-stride) ----------------
__global__ __launch_bounds__(256) void k_conv(const float* __restrict__ s,
                                              _Float16* __restrict__ d, int n4) {
  int i = blockIdx.x * blockDim.x + threadIdx.x;
  int st = gridDim.x * blockDim.x;
  for (; i < n4; i += st) {
    float4 v = ((const float4*)s)[i];
    h16x4 o; o[0] = (_Float16)v.x; o[1] = (_Float16)v.y; o[2] = (_Float16)v.z; o[3] = (_Float16)v.w;
    ((h16x4*)d)[i] = o;
  }
}

// ---------------- embedding gather -> f16 ----------------
__global__ __launch_bounds__(256) void k_gather(const int* __restrict__ tok,
                                                const float* __restrict__ embW,
                                                _Float16* __restrict__ emb) {
  int row = blockIdx.x;                 // row = t*32+b
  int t = tok[row];
  float4 v = ((const float4*)(embW + (size_t)t * EE))[threadIdx.x];
  h16x4 o; o[0] = (_Float16)v.x; o[1] = (_Float16)v.y; o[2] = (_Float16)v.z; o[3] = (_Float16)v.w;
  ((h16x4*)(emb + (size_t)row * EE))[threadIdx.x] = o;
}

// ---------------- pack 4 LDS-resident matrices (Wih1,Whh1,Wih2,Whh2) ----------------
// Wpack4[w][mat][jj][k_lds] = W[layer][row(w,jj)][k_lds ^ ((jj&7)<<3)]  (XOR pre-swizzle)
__global__ __launch_bounds__(256) void k_packw4(const float* __restrict__ Wih,
                                                const float* __restrict__ Whh,
                                                _Float16* __restrict__ out) {
  int i = blockIdx.x * blockDim.x + threadIdx.x;
  int st = gridDim.x * blockDim.x;
  const int total = 256 * 65536;
  for (; i < total; i += st) {
    int w = i >> 16, rem = i & 65535;
    int mat = rem >> 14, jj = (rem >> 10) & 15, k = rem & 1023;
    int layer = 1 + (mat >> 1), isHH = mat & 1;
    int row = ((jj >> 2) << 10) + (w << 2) + (jj & 3);
    int ks = k ^ ((jj & 7) << 3);
    const float* src = (isHH ? Whh : Wih) + (size_t)layer * G4 * 1024 + (size_t)row * 1024 + ks;
    out[i] = (_Float16)(*src);
  }
}

// ---------------- pack Whh0 fragment-linear: [w][ks 0..31][lane 0..63][e 0..7] ----------------
__global__ __launch_bounds__(256) void k_packw0(const float* __restrict__ Whh,
                                                _Float16* __restrict__ out) {
  int i = blockIdx.x * blockDim.x + threadIdx.x;
  int st = gridDim.x * blockDim.x;
  const int total = 256 * 16384;
  for (; i < total; i += st) {
    int w = i >> 14, rem = i & 16383;
    int ks = rem >> 9, lane = (rem >> 3) & 63, e = rem & 7;
    int jj = lane & 15, q = lane >> 4;
    int row = ((jj >> 2) << 10) + (w << 2) + (jj & 3);
    int k = ks * 32 + q * 8 + e;
    out[i] = (_Float16)Whh[(size_t)row * 1024 + k];   // layer 0
  }
}

// ---------------- init: sync flags + initial h fragments ----------------
// parity init per layer: l0 -> slot[0][1], l1 -> slot[1][0], l2 -> slot[2][1]
__global__ __launch_bounds__(256) void k_init(const float* __restrict__ h0,
                                              _Float16* __restrict__ hfrag,
                                              unsigned* __restrict__ sync) {
  int i = blockIdx.x * blockDim.x + threadIdx.x;
  if (i < 64 + 8192) sync[i] = 0u;   // gen (+pad) and all arrive slots
  if (i >= 3 * BB * HH) return;
  int l = i >> 15, rem = i & 32767;
  int b = rem >> 10, n = rem & 1023;
  int parI = (l == 1) ? 0 : 1;
  int tbb = b >> 4, ks = n >> 5, q = (n >> 3) & 3, e = n & 7;
  int lane2 = (b & 15) | (q << 4);
  hfrag[(size_t)(l * 2 + parI) * 32768 + ((size_t)(tbb * 32 + ks) * 64 + lane2) * 8 + e] =
      (_Float16)h0[i];
}

// ---------------- generic 128x128 BT GEMM (A[M,K] f16, B[N,K] f16) ----------------
// staging via global_load_lds width=16 (dest linear in tid per wave: legal form)
// EPI: 0 = f32 + bias1 ; 1 = f16 ; 2 = f16(tanh) ; 3 = f16 + bias1 + bias2
template <int EPI>
__global__ __launch_bounds__(256) void k_gemm(const _Float16* __restrict__ A,
                                              const _Float16* __restrict__ B,
                                              void* __restrict__ C, int M, int N, int K,
                                              const float* __restrict__ bias1,
                                              const float* __restrict__ bias2) {
  __shared__ _Float16 As[2][128 * 32];
  __shared__ _Float16 Bs[2][128 * 32];
  const int ntn = N / 128;
  const int tm = blockIdx.x / ntn, tn = blockIdx.x % ntn;
  const int tid = threadIdx.x, lane = tid & 63;
  const int wv = tid >> 6, wr = wv >> 1, wc = wv & 1;
  f32x4 acc[4][4] = {};

  auto stage = [&](int buf, int k0) {
#pragma unroll
    for (int i = 0; i < 2; ++i) {
      int eo = (i * 256 + tid) * 8;
      int r = eo >> 5, c = eo & 31;
      __builtin_amdgcn_global_load_lds(AS_G(A + (size_t)(tm * 128 + r) * K + k0 + c),
                                       AS_L(&As[buf][eo]), 16, 0, 0);
      __builtin_amdgcn_global_load_lds(AS_G(B + (size_t)(tn * 128 + r) * K + k0 + c),
                                       AS_L(&Bs[buf][eo]), 16, 0, 0);
    }
  };
  stage(0, 0);
  __syncthreads();
  const int nk = K / 32;
  for (int kt = 0; kt < nk; ++kt) {
    if (kt + 1 < nk) stage((kt + 1) & 1, (kt + 1) * 32);
    const int buf = kt & 1;
    h16x8 af[4], bfr[4];
#pragma unroll
    for (int mi = 0; mi < 4; ++mi)
      af[mi] = *(const h16x8*)&As[buf][(wr * 64 + mi * 16 + (lane & 15)) * 32 + (lane >> 4) * 8];
#pragma unroll
    for (int ni = 0; ni < 4; ++ni)
      bfr[ni] = *(const h16x8*)&Bs[buf][(wc * 64 + ni * 16 + (lane & 15)) * 32 + (lane >> 4) * 8];
#pragma unroll
    for (int mi = 0; mi < 4; ++mi)
#pragma unroll
      for (int ni = 0; ni < 4; ++ni)
        acc[mi][ni] = __builtin_amdgcn_mfma_f32_16x16x32_f16(af[mi], bfr[ni], acc[mi][ni], 0, 0, 0);
    __syncthreads();
  }
  const int rbase = tm * 128 + wr * 64;
  const int cbase = tn * 128 + wc * 64;
#pragma unroll
  for (int mi = 0; mi < 4; ++mi) {
#pragma unroll
    for (int ni = 0; ni < 4; ++ni) {
#pragma unroll
      for (int r = 0; r < 4; ++r) {
        int mm = rbase + mi * 16 + (lane >> 4) * 4 + r;
        int nn = cbase + ni * 16 + (lane & 15);
        float v = acc[mi][ni][r];
        if (EPI == 0) {
          ((float*)C)[(size_t)mm * N + nn] = v + bias1[nn];
        } else if (EPI == 1) {
          ((_Float16*)C)[(size_t)mm * N + nn] = (_Float16)v;
        } else if (EPI == 2) {
          ((_Float16*)C)[(size_t)mm * N + nn] = (_Float16)tanhf(v);
        } else {
          ((_Float16*)C)[(size_t)mm * N + nn] = (_Float16)(v + bias1[nn] + bias2[nn]);
        }
      }
    }
  }
}

// ---------------- grid barrier v2: per-wg arrival flags, wg0 lane-parallel poll ----------------
// arrive[w*32] (128B stride); gen = sync[0]. No same-address atomic contention.
__device__ __forceinline__ void grid_barrier2(unsigned* __restrict__ sync, unsigned target) {
  unsigned* gen = sync;
  unsigned* arrive = sync + 64;
  __syncthreads();
  if (blockIdx.x == 0) {
    if (threadIdx.x == 0)
      __hip_atomic_store(&arrive[0], target, __ATOMIC_RELEASE, __HIP_MEMORY_SCOPE_AGENT);
    if (threadIdx.x < 64) {
      for (;;) {
        bool ok = true;
#pragma unroll
        for (int j = 0; j < 4; ++j) {
          unsigned v = __hip_atomic_load(&arrive[(threadIdx.x * 4 + j) * 32],
                                         __ATOMIC_RELAXED, __HIP_MEMORY_SCOPE_AGENT);
          ok &= (v >= target);
        }
        if (__all(ok)) break;
        __builtin_amdgcn_s_sleep(1);
      }
      if (threadIdx.x == 0) {
        __threadfence();  // acquire for wg0's own subsequent reads
        __hip_atomic_store(gen, target, __ATOMIC_RELEASE, __HIP_MEMORY_SCOPE_AGENT);
      }
    }
  } else {
    if (threadIdx.x == 0) {
      __hip_atomic_store(&arrive[blockIdx.x * 32], target, __ATOMIC_RELEASE,
                         __HIP_MEMORY_SCOPE_AGENT);
      for (;;) {
        unsigned g = __hip_atomic_load(gen, __ATOMIC_RELAXED, __HIP_MEMORY_SCOPE_AGENT);
        if (g >= target) break;
        __builtin_amdgcn_s_sleep(1);
      }
      __threadfence();  // acquire
    }
  }
  __syncthreads();
}

// ---------------- persistent pipelined LSTM recurrence ----------------
// 256 wgs x 512 thr. wg w owns hidden units n = 4w..4w+3 (16 gate rows).
// Tick tau: l0 computes h0(tau), l1 computes h1(tau-1), l2 computes h2(tau-2).
// LDS: Wih1|Whh1|Wih2|Whh2 (128KB, XOR-swizzled) + redbuf(18KB) + gbuf(6KB).
// Regular launch; co-residency structural: 152KB LDS => 1 wg/CU, grid 256 == CU count.
__global__ __launch_bounds__(512) void k_recur(const _Float16* __restrict__ Wp4,
                                               const _Float16* __restrict__ Wp0,
                                               const _Float16* __restrict__ X0bf,
                                               _Float16* __restrict__ hfrag,
                                               _Float16* __restrict__ h2all,
                                               _Float16* __restrict__ concat,
                                               const float* __restrict__ bih,
                                               const float* __restrict__ bhh,
                                               const float* __restrict__ c0p,
                                               unsigned* __restrict__ sync) {
  extern __shared__ char lds[];
  _Float16* ldsW = (_Float16*)lds;                 // 65536 f16
  float* redbuf = (float*)(lds + 131072);          // [3][3][2][256]
  float* gbuf = (float*)(lds + 149504);            // [3][32][16]

  const int w = blockIdx.x;
  const int tid = threadIdx.x, lane = tid & 63, wv = tid >> 6;
  const int tb = wv & 1, kq = wv >> 1;
  const int row = (lane >> 4) * 4, col = lane & 15;

  // preload LDS weights (linear copy; swizzle pre-applied by k_packw4)
  for (int i = 0; i < 16; ++i) {
    int eo = (i * 512 + tid) * 8;
    *(h16x8*)&ldsW[eo] = *(const h16x8*)(Wp4 + (size_t)w * 65536 + eo);
  }
  // Whh0 fragments in registers
  h16x8 w0reg[8];
#pragma unroll
  for (int i = 0; i < 8; ++i)
    w0reg[i] = *(const h16x8*)(Wp0 + (size_t)w * 16384 + ((size_t)(kq * 8 + i) * 64 + lane) * 8);

  // per-thread epilogue state (threads 0..127 own (b, ni))
  const int eb = tid >> 2, eni = tid & 3, en = w * 4 + eni;
  int hoff = 0;
  float c0r = 0.f, c1r = 0.f, c2r = 0.f;
  float b1r[4] = {0, 0, 0, 0}, b2r[4] = {0, 0, 0, 0};
  if (tid < 128) {
    int tbb = eb >> 4, ks2 = en >> 5, q2 = (en >> 3) & 3, e2 = en & 7;
    int lane2 = (eb & 15) | (q2 << 4);
    hoff = ((tbb * 32 + ks2) * 64 + lane2) * 8 + e2;
    c0r = c0p[0 * BB * HH + eb * HH + en];
    c1r = c0p[1 * BB * HH + eb * HH + en];
    c2r = c0p[2 * BB * HH + eb * HH + en];
#pragma unroll
    for (int g = 0; g < 4; ++g) {
      b1r[g] = bih[1 * G4 + g * 1024 + en] + bhh[1 * G4 + g * 1024 + en];
      b2r[g] = bih[2 * G4 + g * 1024 + en] + bhh[2 * G4 + g * 1024 + en];
    }
  }
  __syncthreads();

  for (int tau = 0; tau < 130; ++tau) {
    const int p = tau & 1;
    const _Float16* h0r = hfrag + (size_t)(0 + (1 - p)) * 32768;
    const _Float16* h1r = hfrag + (size_t)(2 + (1 - p)) * 32768;
    const _Float16* h2r = hfrag + (size_t)(4 + (1 - p)) * 32768;

    // A fragments (coalesced 16B/lane); inactive-layer reads feed discarded accs
    h16x8 a0[8], a1[8], a2[8];
#pragma unroll
    for (int i = 0; i < 8; ++i) {
      int ks = kq * 8 + i;
      size_t off = ((size_t)(tb * 32 + ks) * 64 + lane) * 8;
      a0[i] = *(const h16x8*)(h0r + off);
      a1[i] = *(const h16x8*)(h1r + off);
      a2[i] = *(const h16x8*)(h2r + off);
    }
    // hoist X0 gate loads: LLC latency hides under fragment loads + MFMA
    float xg0 = 0.f, xg1 = 0.f, xg2 = 0.f, xg3 = 0.f;
    if (tid < 128 && tau < 128) {
      size_t xb = ((size_t)(tau * BB + eb)) * G4 + en;
      xg0 = (float)X0bf[xb];        xg1 = (float)X0bf[xb + 1024];
      xg2 = (float)X0bf[xb + 2048]; xg3 = (float)X0bf[xb + 3072];
    }
    f32x4 acc0 = {}, acc1 = {}, acc2 = {};
#pragma unroll
    for (int i = 0; i < 8; ++i) {
      int ks = kq * 8 + i;
      int jj = lane & 15, q = lane >> 4;
      int kk = (ks * 32 + q * 8) ^ ((jj & 7) << 3);
      const h16x8 bw1i = *(const h16x8*)&ldsW[0 * 16384 + jj * 1024 + kk];
      const h16x8 bw1h = *(const h16x8*)&ldsW[1 * 16384 + jj * 1024 + kk];
      const h16x8 bw2i = *(const h16x8*)&ldsW[2 * 16384 + jj * 1024 + kk];
      const h16x8 bw2h = *(const h16x8*)&ldsW[3 * 16384 + jj * 1024 + kk];
      acc0 = __builtin_amdgcn_mfma_f32_16x16x32_f16(a0[i], w0reg[i], acc0, 0, 0, 0);
      acc1 = __builtin_amdgcn_mfma_f32_16x16x32_f16(a0[i], bw1i, acc1, 0, 0, 0);
      acc1 = __builtin_amdgcn_mfma_f32_16x16x32_f16(a1[i], bw1h, acc1, 0, 0, 0);
      acc2 = __builtin_amdgcn_mfma_f32_16x16x32_f16(a1[i], bw2i, acc2, 0, 0, 0);
      acc2 = __builtin_amdgcn_mfma_f32_16x16x32_f16(a2[i], bw2h, acc2, 0, 0, 0);
    }
    // cross-wave K reduction
    if (kq >= 1) {
      int s = kq - 1;
#pragma unroll
      for (int r = 0; r < 4; ++r) {
        redbuf[((0 * 3 + s) * 2 + tb) * 256 + (row + r) * 16 + col] = acc0[r];
        redbuf[((1 * 3 + s) * 2 + tb) * 256 + (row + r) * 16 + col] = acc1[r];
        redbuf[((2 * 3 + s) * 2 + tb) * 256 + (row + r) * 16 + col] = acc2[r];
      }
    }
    __syncthreads();
    if (kq == 0) {
#pragma unroll
      for (int r = 0; r < 4; ++r) {
        float v0 = acc0[r], v1 = acc1[r], v2 = acc2[r];
#pragma unroll
        for (int s = 0; s < 3; ++s) {
          v0 += redbuf[((0 * 3 + s) * 2 + tb) * 256 + (row + r) * 16 + col];
          v1 += redbuf[((1 * 3 + s) * 2 + tb) * 256 + (row + r) * 16 + col];
          v2 += redbuf[((2 * 3 + s) * 2 + tb) * 256 + (row + r) * 16 + col];
        }
        gbuf[(0 * 32 + tb * 16 + row + r) * 16 + col] = v0;
        gbuf[(1 * 32 + tb * 16 + row + r) * 16 + col] = v1;
        gbuf[(2 * 32 + tb * 16 + row + r) * 16 + col] = v2;
      }
    }
    __syncthreads();
    // elementwise LSTM epilogue
    if (tid < 128) {
      if (tau < 128) {  // layer 0: X0 already holds x@Wih0^T + b_ih0 + b_hh0
        float gi = gbuf[(0 * 32 + eb) * 16 + eni] + xg0;
        float gf = gbuf[(0 * 32 + eb) * 16 + 4 + eni] + xg1;
        float gg = gbuf[(0 * 32 + eb) * 16 + 8 + eni] + xg2;
        float go = gbuf[(0 * 32 + eb) * 16 + 12 + eni] + xg3;
        c0r = sigmf(gf) * c0r + sigmf(gi) * tanhf(gg);
        float h = sigmf(go) * tanhf(c0r);
        hfrag[(size_t)(0 + p) * 32768 + hoff] = (_Float16)h;
      }
      if (tau >= 1 && tau < 129) {  // layer 1
        float gi = gbuf[(1 * 32 + eb) * 16 + eni] + b1r[0];
        float gf = gbuf[(1 * 32 + eb) * 16 + 4 + eni] + b1r[1];
        float gg = gbuf[(1 * 32 + eb) * 16 + 8 + eni] + b1r[2];
        float go = gbuf[(1 * 32 + eb) * 16 + 12 + eni] + b1r[3];
        c1r = sigmf(gf) * c1r + sigmf(gi) * tanhf(gg);
        float h = sigmf(go) * tanhf(c1r);
        hfrag[(size_t)(2 + p) * 32768 + hoff] = (_Float16)h;
      }
      if (tau >= 2) {  // layer 2
        float gi = gbuf[(2 * 32 + eb) * 16 + eni] + b2r[0];
        float gf = gbuf[(2 * 32 + eb) * 16 + 4 + eni] + b2r[1];
        float gg = gbuf[(2 * 32 + eb) * 16 + 8 + eni] + b2r[2];
        float go = gbuf[(2 * 32 + eb) * 16 + 12 + eni] + b2r[3];
        c2r = sigmf(gf) * c2r + sigmf(gi) * tanhf(gg);
        float h = sigmf(go) * tanhf(c2r);
        _Float16 hb = (_Float16)h;
        hfrag[(size_t)(4 + p) * 32768 + hoff] = hb;
        int t2 = tau - 2;
        h2all[(size_t)(t2 * BB + eb) * HH + en] = hb;
        concat[(size_t)(t2 * BB + eb) * 2048 + 1024 + en] = hb;
      }
    }
    grid_barrier2(sync, (unsigned)(tau + 1));
  }
}

// ---------------- fused scores+softmax+weighted-context per (t,b) ----------------
__global__ __launch_bounds__(256) void k_attn(const _Float16* __restrict__ target,
                                              const _Float16* __restrict__ encb,
                                              _Float16* __restrict__ concat) {
  __shared__ float sc[64];
  __shared__ float att[64];
  int m = blockIdx.x, b = m & 31;
  int tid = threadIdx.x, lane = tid & 63, wv = tid >> 6;
  const h16x8* tp = (const h16x8*)(target + (size_t)m * EE + lane * 16);
  h16x8 tg0 = tp[0], tg1 = tp[1];
  for (int si = 0; si < 16; ++si) {
    int s = wv * 16 + si;
    const h16x8* ep = (const h16x8*)(encb + ((size_t)s * BB + b) * EE + lane * 16);
    h16x8 e0 = ep[0], e1 = ep[1];
    float a = 0.f;
#pragma unroll
    for (int j = 0; j < 8; ++j) a += (float)e0[j] * (float)tg0[j];
#pragma unroll
    for (int j = 0; j < 8; ++j) a += (float)e1[j] * (float)tg1[j];
#pragma unroll
    for (int off = 32; off >= 1; off >>= 1) a += __shfl_xor(a, off);
    if (lane == 0) sc[s] = a;
  }
  __syncthreads();
  if (wv == 0) {
    float v = sc[lane], mx = v;
#pragma unroll
    for (int off = 32; off >= 1; off >>= 1) mx = fmaxf(mx, __shfl_xor(mx, off));
    float e = expf(v - mx), sm = e;
#pragma unroll
    for (int off = 32; off >= 1; off >>= 1) sm += __shfl_xor(sm, off);
    att[lane] = e / sm;
  }
  __syncthreads();
  int e4 = tid * 4;
  float a0 = 0, a1 = 0, a2 = 0, a3 = 0;
  for (int s = 0; s < 64; ++s) {
    float wgt = att[s];
    h16x4 ev = *(const h16x4*)(encb + ((size_t)s * BB + b) * EE + e4);
    a0 += wgt * (float)ev[0]; a1 += wgt * (float)ev[1];
    a2 += wgt * (float)ev[2]; a3 += wgt * (float)ev[3];
  }
  h16x4 o; o[0] = (_Float16)a0; o[1] = (_Float16)a1; o[2] = (_Float16)a2; o[3] = (_Float16)a3;
  *(h16x4*)(concat + (size_t)m * 2048 + e4) = o;
}

// ---------------- host ----------------
extern "C" void kernel_launch(void* const* d_in, const int* in_sizes, int n_in,
                              void* d_out, int out_size, void* d_ws, size_t ws_size,
                              hipStream_t stream) {
  const int* tokens = (const int*)d_in[0];
  const float* embW = (const float*)d_in[1];
  const float* Wih = (const float*)d_in[2];
  const float* Whh = (const float*)d_in[3];
  const float* bih = (const float*)d_in[4];
  const float* bhh = (const float*)d_in[5];
  const float* Win = (const float*)d_in[6];
  const float* Wout = (const float*)d_in[7];
  const float* finalb = (const float*)d_in[8];
  const float* enc = (const float*)d_in[9];
  const float* h0 = (const float*)d_in[10];
  const float* c0 = (const float*)d_in[11];
  (void)in_sizes; (void)n_in; (void)out_size;
  if (ws_size < WS_NEEDED) return;

  char* ws = (char*)d_ws;
  unsigned* sync = (unsigned*)(ws + OFF_SYNC);
  _Float16* hfrag = (_Float16*)(ws + OFF_HFRAG);
  _Float16* emb = (_Float16*)(ws + OFF_EMB);
  _Float16* X0bf = (_Float16*)(ws + OFF_X0);
  _Float16* Wih0b = (_Float16*)(ws + OFF_WIH0);
  _Float16* Wp4 = (_Float16*)(ws + OFF_WP4);
  _Float16* Wp0 = (_Float16*)(ws + OFF_WP0);
  _Float16* embWb = (_Float16*)(ws + OFF_EMBW);
  _Float16* Winb = (_Float16*)(ws + OFF_WIN);
  _Float16* Woutb = (_Float16*)(ws + OFF_WOUT);
  _Float16* encb = (_Float16*)(ws + OFF_ENC);
  _Float16* h2all = (_Float16*)(ws + OFF_H2ALL);
  _Float16* concat = (_Float16*)(ws + OFF_CONCAT);
  _Float16* target = (_Float16*)(ws + OFF_TARGET);
  _Float16* ht = (_Float16*)(ws + OFF_HT);

  const unsigned LDSB = 155648;  // 128KB weights + 18KB redbuf + 6KB gbuf
  static int lds_set = 0;
  if (!lds_set) {
    hipFuncSetAttribute((const void*)k_recur, hipFuncAttributeMaxDynamicSharedMemorySize,
                        (int)LDSB);
    lds_set = 1;   // attribute is sticky on the function; setting once is enough
  }

  // prep: converts / packs / init
  k_conv<<<4096, 256, 0, stream>>>(embW, embWb, VV * EE / 4);
  k_conv<<<1024, 256, 0, stream>>>(Wih, Wih0b, G4 * EE / 4);       // layer-0 W_ih
  k_conv<<<512, 256, 0, stream>>>(Win, Winb, EE * EE / 4);
  k_conv<<<512, 256, 0, stream>>>(Wout, Woutb, EE * 2048 / 4);
  k_conv<<<512, 256, 0, stream>>>(enc, encb, 64 * BB * EE / 4);
  k_gather<<<NROWS, 256, 0, stream>>>(tokens, embW, emb);
  k_packw4<<<8192, 256, 0, stream>>>(Wih, Whh, Wp4);
  k_packw0<<<4096, 256, 0, stream>>>(Whh, Wp0);
  k_init<<<384, 256, 0, stream>>>(h0, hfrag, sync);

  // X0 = emb @ Wih0^T + b_ih0 + b_hh0   -> f16 [4096,4096]
  k_gemm<3><<<32 * 32, 256, 0, stream>>>(emb, Wih0b, X0bf, NROWS, G4, EE, bih, bhh);

  // recurrence: REGULAR launch (graph-capturable); co-residency structural
  k_recur<<<256, 512, LDSB, stream>>>(Wp4, Wp0, X0bf, hfrag, h2all, concat,
                                      bih, bhh, c0, sync);

  // attention chain
  k_gemm<1><<<32 * 8, 256, 0, stream>>>(h2all, Winb, target, NROWS, EE, EE, nullptr, nullptr);
  k_attn<<<NROWS, 256, 0, stream>>>(target, encb, concat);
  k_gemm<2><<<32 * 8, 256, 0, stream>>>(concat, Woutb, ht, NROWS, EE, 2048, nullptr, nullptr);

  // logits = ht @ embW^T + final_b  -> f32 d_out
  k_gemm<0><<<32 * 250, 256, 0, stream>>>(ht, embWb, d_out, NROWS, VV, EE, finalb, nullptr);
}

// Round 5
// 1724.272 us; speedup vs baseline: 2.8778x; 1.6707x over previous
//
#include <hip/hip_runtime.h>
#include <cstdint>
#include <cstddef>

#define SEQ   128
#define BB    32
#define EE    1024
#define HH    1024
#define G4    4096
#define VV    32000
#define NROWS 4096   // SEQ*BB

typedef _Float16 h16x8 __attribute__((ext_vector_type(8)));
typedef _Float16 h16x4 __attribute__((ext_vector_type(4)));
typedef float f32x4  __attribute__((ext_vector_type(4)));

#define AS_G(p) ((const __attribute__((address_space(1))) void*)(p))
#define AS_L(p) ((__attribute__((address_space(3))) void*)(p))

__device__ __forceinline__ float sigmf(float x) { return 1.0f / (1.0f + expf(-x)); }

// ---------------- ws layout (bytes) ----------------
// sync region: 64 dwords pad @0, arrive[256] @256 stride 128B (32KB)
#define OFF_SYNC    0ull
#define OFF_HFRAG   33024ull                  // 6 slots * 32768 f16 = 393216 B
#define OFF_EMB     426240ull                 // [4096][1024] f16
#define OFF_X0      8814848ull                // [4096][4096] f16
#define OFF_WIH0    42369280ull               // [4096][1024] f16
#define OFF_WP4     50757888ull               // 256 wg * 65536 f16
#define OFF_WP0     84312320ull               // 256 wg * 16384 f16
#define OFF_EMBW    92700928ull               // [32000][1024] f16
#define OFF_WIN     158236928ull              // [1024][1024] f16
#define OFF_WOUT    160334080ull              // [1024][2048] f16
#define OFF_ENC     164528384ull              // [64][32][1024] f16
#define OFF_H2ALL   168722688ull              // [4096][1024] f16
#define OFF_CONCAT  177111296ull              // [4096][2048] f16
#define OFF_TARGET  193888512ull              // [4096][1024] f16
#define OFF_HT      202277120ull              // [4096][1024] f16
#define WS_NEEDED   210665728ull

// ---------------- f32 -> f16 convert (vectorized, grid-stride) ----------------
__global__ __launch_bounds__(256) void k_conv(const float* __restrict__ s,
                                              _Float16* __restrict__ d, int n4) {
  int i = blockIdx.x * blockDim.x + threadIdx.x;
  int st = gridDim.x * blockDim.x;
  for (; i < n4; i += st) {
    float4 v = ((const float4*)s)[i];
    h16x4 o; o[0] = (_Float16)v.x; o[1] = (_Float16)v.y; o[2] = (_Float16)v.z; o[3] = (_Float16)v.w;
    ((h16x4*)d)[i] = o;
  }
}

// ---------------- embedding gather -> f16 ----------------
__global__ __launch_bounds__(256) void k_gather(const int* __restrict__ tok,
                                                const float* __restrict__ embW,
                                                _Float16* __restrict__ emb) {
  int row = blockIdx.x;                 // row = t*32+b
  int t = tok[row];
  float4 v = ((const float4*)(embW + (size_t)t * EE))[threadIdx.x];
  h16x4 o; o[0] = (_Float16)v.x; o[1] = (_Float16)v.y; o[2] = (_Float16)v.z; o[3] = (_Float16)v.w;
  ((h16x4*)(emb + (size_t)row * EE))[threadIdx.x] = o;
}

// ---------------- pack 4 LDS-resident matrices (Wih1,Whh1,Wih2,Whh2) ----------------
// Wpack4[w][mat][jj][k_lds] = W[layer][row(w,jj)][k_lds ^ ((jj&7)<<3)]  (XOR pre-swizzle)
__global__ __launch_bounds__(256) void k_packw4(const float* __restrict__ Wih,
                                                const float* __restrict__ Whh,
                                                _Float16* __restrict__ out) {
  int i = blockIdx.x * blockDim.x + threadIdx.x;
  int st = gridDim.x * blockDim.x;
  const int total = 256 * 65536;
  for (; i < total; i += st) {
    int w = i >> 16, rem = i & 65535;
    int mat = rem >> 14, jj = (rem >> 10) & 15, k = rem & 1023;
    int layer = 1 + (mat >> 1), isHH = mat & 1;
    int row = ((jj >> 2) << 10) + (w << 2) + (jj & 3);
    int ks = k ^ ((jj & 7) << 3);
    const float* src = (isHH ? Whh : Wih) + (size_t)layer * G4 * 1024 + (size_t)row * 1024 + ks;
    out[i] = (_Float16)(*src);
  }
}

// ---------------- pack Whh0 fragment-linear: [w][ks 0..31][lane 0..63][e 0..7] ----------------
__global__ __launch_bounds__(256) void k_packw0(const float* __restrict__ Whh,
                                                _Float16* __restrict__ out) {
  int i = blockIdx.x * blockDim.x + threadIdx.x;
  int st = gridDim.x * blockDim.x;
  const int total = 256 * 16384;
  for (; i < total; i += st) {
    int w = i >> 14, rem = i & 16383;
    int ks = rem >> 9, lane = (rem >> 3) & 63, e = rem & 7;
    int jj = lane & 15, q = lane >> 4;
    int row = ((jj >> 2) << 10) + (w << 2) + (jj & 3);
    int k = ks * 32 + q * 8 + e;
    out[i] = (_Float16)Whh[(size_t)row * 1024 + k];   // layer 0
  }
}

// ---------------- init: sync flags + initial h fragments ----------------
// parity init per layer: l0 -> slot[0][1], l1 -> slot[1][0], l2 -> slot[2][1]
__global__ __launch_bounds__(256) void k_init(const float* __restrict__ h0,
                                              _Float16* __restrict__ hfrag,
                                              unsigned* __restrict__ sync) {
  int i = blockIdx.x * blockDim.x + threadIdx.x;
  if (i < 64 + 8192) sync[i] = 0u;   // pad + all arrive slots
  if (i >= 3 * BB * HH) return;
  int l = i >> 15, rem = i & 32767;
  int b = rem >> 10, n = rem & 1023;
  int parI = (l == 1) ? 0 : 1;
  int tbb = b >> 4, ks = n >> 5, q = (n >> 3) & 3, e = n & 7;
  int lane2 = (b & 15) | (q << 4);
  hfrag[(size_t)(l * 2 + parI) * 32768 + ((size_t)(tbb * 32 + ks) * 64 + lane2) * 8 + e] =
      (_Float16)h0[i];
}

// ---------------- generic 128x128 BT GEMM (A[M,K] f16, B[N,K] f16) ----------------
// staging via global_load_lds width=16 (dest linear in tid per wave: legal form)
// EPI: 0 = f32 + bias1 ; 1 = f16 ; 2 = f16(tanh) ; 3 = f16 + bias1 + bias2
template <int EPI>
__global__ __launch_bounds__(256) void k_gemm(const _Float16* __restrict__ A,
                                              const _Float16* __restrict__ B,
                                              void* __restrict__ C, int M, int N, int K,
                                              const float* __restrict__ bias1,
                                              const float* __restrict__ bias2) {
  __shared__ _Float16 As[2][128 * 32];
  __shared__ _Float16 Bs[2][128 * 32];
  const int ntn = N / 128;
  const int tm = blockIdx.x / ntn, tn = blockIdx.x % ntn;
  const int tid = threadIdx.x, lane = tid & 63;
  const int wv = tid >> 6, wr = wv >> 1, wc = wv & 1;
  f32x4 acc[4][4] = {};

  auto stage = [&](int buf, int k0) {
#pragma unroll
    for (int i = 0; i < 2; ++i) {
      int eo = (i * 256 + tid) * 8;
      int r = eo >> 5, c = eo & 31;
      __builtin_amdgcn_global_load_lds(AS_G(A + (size_t)(tm * 128 + r) * K + k0 + c),
                                       AS_L(&As[buf][eo]), 16, 0, 0);
      __builtin_amdgcn_global_load_lds(AS_G(B + (size_t)(tn * 128 + r) * K + k0 + c),
                                       AS_L(&Bs[buf][eo]), 16, 0, 0);
    }
  };
  stage(0, 0);
  __syncthreads();
  const int nk = K / 32;
  for (int kt = 0; kt < nk; ++kt) {
    if (kt + 1 < nk) stage((kt + 1) & 1, (kt + 1) * 32);
    const int buf = kt & 1;
    h16x8 af[4], bfr[4];
#pragma unroll
    for (int mi = 0; mi < 4; ++mi)
      af[mi] = *(const h16x8*)&As[buf][(wr * 64 + mi * 16 + (lane & 15)) * 32 + (lane >> 4) * 8];
#pragma unroll
    for (int ni = 0; ni < 4; ++ni)
      bfr[ni] = *(const h16x8*)&Bs[buf][(wc * 64 + ni * 16 + (lane & 15)) * 32 + (lane >> 4) * 8];
#pragma unroll
    for (int mi = 0; mi < 4; ++mi)
#pragma unroll
      for (int ni = 0; ni < 4; ++ni)
        acc[mi][ni] = __builtin_amdgcn_mfma_f32_16x16x32_f16(af[mi], bfr[ni], acc[mi][ni], 0, 0, 0);
    __syncthreads();
  }
  const int rbase = tm * 128 + wr * 64;
  const int cbase = tn * 128 + wc * 64;
#pragma unroll
  for (int mi = 0; mi < 4; ++mi) {
#pragma unroll
    for (int ni = 0; ni < 4; ++ni) {
#pragma unroll
      for (int r = 0; r < 4; ++r) {
        int mm = rbase + mi * 16 + (lane >> 4) * 4 + r;
        int nn = cbase + ni * 16 + (lane & 15);
        float v = acc[mi][ni][r];
        if (EPI == 0) {
          ((float*)C)[(size_t)mm * N + nn] = v + bias1[nn];
        } else if (EPI == 1) {
          ((_Float16*)C)[(size_t)mm * N + nn] = (_Float16)v;
        } else if (EPI == 2) {
          ((_Float16*)C)[(size_t)mm * N + nn] = (_Float16)tanhf(v);
        } else {
          ((_Float16*)C)[(size_t)mm * N + nn] = (_Float16)(v + bias1[nn] + bias2[nn]);
        }
      }
    }
  }
}

// ---------------- persistent pipelined LSTM recurrence ----------------
// 256 wgs x 512 thr. wg w owns hidden units n = 4w..4w+3 (16 gate rows).
// Tick tau: l0 computes h0(tau), l1 computes h1(tau-1), l2 computes h2(tau-2).
// Fence-free exchange: h data via agent-scope (sc1) 8B atomic stores (no L2
// writeback), relaxed flag after explicit vmcnt(0)+barrier; readers do one
// acquire-inv then use normal cached loads (L2-amortized per XCD).
// Regular launch; co-residency structural: 152KB LDS => 1 wg/CU, grid 256 == CU count.
__global__ __launch_bounds__(512) void k_recur(const _Float16* __restrict__ Wp4,
                                               const _Float16* __restrict__ Wp0,
                                               const _Float16* __restrict__ X0bf,
                                               _Float16* __restrict__ hfrag,
                                               _Float16* __restrict__ h2all,
                                               _Float16* __restrict__ concat,
                                               const float* __restrict__ bih,
                                               const float* __restrict__ bhh,
                                               const float* __restrict__ c0p,
                                               unsigned* __restrict__ sync) {
  extern __shared__ char lds[];
  _Float16* ldsW = (_Float16*)lds;                 // 65536 f16
  float* redbuf = (float*)(lds + 131072);          // [3][3][2][256]
  _Float16* hstage = (_Float16*)(lds + 131072);    // [3][32][4] (reused after redbuf)
  float* gbuf = (float*)(lds + 149504);            // [3][32][16]
  unsigned* arrive = sync + 64;

  const int w = blockIdx.x;
  const int tid = threadIdx.x, lane = tid & 63, wv = tid >> 6;
  const int tb = wv & 1, kq = wv >> 1;
  const int row = (lane >> 4) * 4, col = lane & 15;

  // preload LDS weights (linear copy; swizzle pre-applied by k_packw4)
  for (int i = 0; i < 16; ++i) {
    int eo = (i * 512 + tid) * 8;
    *(h16x8*)&ldsW[eo] = *(const h16x8*)(Wp4 + (size_t)w * 65536 + eo);
  }
  // Whh0 fragments in registers
  h16x8 w0reg[8];
#pragma unroll
  for (int i = 0; i < 8; ++i)
    w0reg[i] = *(const h16x8*)(Wp0 + (size_t)w * 16384 + ((size_t)(kq * 8 + i) * 64 + lane) * 8);

  // per-thread epilogue state (threads 0..127 own (b, ni))
  const int eb = tid >> 2, eni = tid & 3, en = w * 4 + eni;
  float c0r = 0.f, c1r = 0.f, c2r = 0.f;
  float b1r[4] = {0, 0, 0, 0}, b2r[4] = {0, 0, 0, 0};
  if (tid < 128) {
    c0r = c0p[0 * BB * HH + eb * HH + en];
    c1r = c0p[1 * BB * HH + eb * HH + en];
    c2r = c0p[2 * BB * HH + eb * HH + en];
#pragma unroll
    for (int g = 0; g < 4; ++g) {
      b1r[g] = bih[1 * G4 + g * 1024 + en] + bhh[1 * G4 + g * 1024 + en];
      b2r[g] = bih[2 * G4 + g * 1024 + en] + bhh[2 * G4 + g * 1024 + en];
    }
  }
  // pack-phase constants: h slot offset for 8B run r (=batch row) of this wg
  // en=4w+eni: ks2=w>>3, q2=(w>>1)&3, e2=4*(w&1)+eni; lane2=(eb&15)|(q2<<4)
  const int pk_l = tid >> 5, pk_r = tid & 31;
  const size_t pk_idx = ((size_t)(((pk_r >> 4) * 32 + (w >> 3)) * 64 + (pk_r & 15) +
                                  (((w >> 1) & 3) << 4))) * 8 + 4 * (w & 1);
  __syncthreads();

  for (int tau = 0; tau < 130; ++tau) {
    const int p = tau & 1;
    const _Float16* h0r = hfrag + (size_t)(0 + (1 - p)) * 32768;
    const _Float16* h1r = hfrag + (size_t)(2 + (1 - p)) * 32768;
    const _Float16* h2r = hfrag + (size_t)(4 + (1 - p)) * 32768;

    // A fragments (coalesced 16B/lane); inactive-layer reads feed discarded accs
    h16x8 a0[8], a1[8], a2[8];
#pragma unroll
    for (int i = 0; i < 8; ++i) {
      int ks = kq * 8 + i;
      size_t off = ((size_t)(tb * 32 + ks) * 64 + lane) * 8;
      a0[i] = *(const h16x8*)(h0r + off);
      a1[i] = *(const h16x8*)(h1r + off);
      a2[i] = *(const h16x8*)(h2r + off);
    }
    // hoist X0 gate loads: LLC latency hides under fragment loads + MFMA
    float xg0 = 0.f, xg1 = 0.f, xg2 = 0.f, xg3 = 0.f;
    if (tid < 128 && tau < 128) {
      size_t xb = ((size_t)(tau * BB + eb)) * G4 + en;
      xg0 = (float)X0bf[xb];        xg1 = (float)X0bf[xb + 1024];
      xg2 = (float)X0bf[xb + 2048]; xg3 = (float)X0bf[xb + 3072];
    }
    f32x4 acc0 = {}, acc1 = {}, acc2 = {};
#pragma unroll
    for (int i = 0; i < 8; ++i) {
      int ks = kq * 8 + i;
      int jj = lane & 15, q = lane >> 4;
      int kk = (ks * 32 + q * 8) ^ ((jj & 7) << 3);
      const h16x8 bw1i = *(const h16x8*)&ldsW[0 * 16384 + jj * 1024 + kk];
      const h16x8 bw1h = *(const h16x8*)&ldsW[1 * 16384 + jj * 1024 + kk];
      const h16x8 bw2i = *(const h16x8*)&ldsW[2 * 16384 + jj * 1024 + kk];
      const h16x8 bw2h = *(const h16x8*)&ldsW[3 * 16384 + jj * 1024 + kk];
      acc0 = __builtin_amdgcn_mfma_f32_16x16x32_f16(a0[i], w0reg[i], acc0, 0, 0, 0);
      acc1 = __builtin_amdgcn_mfma_f32_16x16x32_f16(a0[i], bw1i, acc1, 0, 0, 0);
      acc1 = __builtin_amdgcn_mfma_f32_16x16x32_f16(a1[i], bw1h, acc1, 0, 0, 0);
      acc2 = __builtin_amdgcn_mfma_f32_16x16x32_f16(a1[i], bw2i, acc2, 0, 0, 0);
      acc2 = __builtin_amdgcn_mfma_f32_16x16x32_f16(a2[i], bw2h, acc2, 0, 0, 0);
    }
    // cross-wave K reduction
    if (kq >= 1) {
      int s = kq - 1;
#pragma unroll
      for (int r = 0; r < 4; ++r) {
        redbuf[((0 * 3 + s) * 2 + tb) * 256 + (row + r) * 16 + col] = acc0[r];
        redbuf[((1 * 3 + s) * 2 + tb) * 256 + (row + r) * 16 + col] = acc1[r];
        redbuf[((2 * 3 + s) * 2 + tb) * 256 + (row + r) * 16 + col] = acc2[r];
      }
    }
    __syncthreads();
    if (kq == 0) {
#pragma unroll
      for (int r = 0; r < 4; ++r) {
        float v0 = acc0[r], v1 = acc1[r], v2 = acc2[r];
#pragma unroll
        for (int s = 0; s < 3; ++s) {
          v0 += redbuf[((0 * 3 + s) * 2 + tb) * 256 + (row + r) * 16 + col];
          v1 += redbuf[((1 * 3 + s) * 2 + tb) * 256 + (row + r) * 16 + col];
          v2 += redbuf[((2 * 3 + s) * 2 + tb) * 256 + (row + r) * 16 + col];
        }
        gbuf[(0 * 32 + tb * 16 + row + r) * 16 + col] = v0;
        gbuf[(1 * 32 + tb * 16 + row + r) * 16 + col] = v1;
        gbuf[(2 * 32 + tb * 16 + row + r) * 16 + col] = v2;
      }
    }
    __syncthreads();
    // elementwise LSTM epilogue -> hstage (LDS) + h2all/concat (regular stores)
    if (tid < 128) {
      if (tau < 128) {  // layer 0: X0 already holds x@Wih0^T + b_ih0 + b_hh0
        float gi = gbuf[(0 * 32 + eb) * 16 + eni] + xg0;
        float gf = gbuf[(0 * 32 + eb) * 16 + 4 + eni] + xg1;
        float gg = gbuf[(0 * 32 + eb) * 16 + 8 + eni] + xg2;
        float go = gbuf[(0 * 32 + eb) * 16 + 12 + eni] + xg3;
        c0r = sigmf(gf) * c0r + sigmf(gi) * tanhf(gg);
        hstage[0 * 128 + tid] = (_Float16)(sigmf(go) * tanhf(c0r));
      }
      if (tau >= 1 && tau < 129) {  // layer 1
        float gi = gbuf[(1 * 32 + eb) * 16 + eni] + b1r[0];
        float gf = gbuf[(1 * 32 + eb) * 16 + 4 + eni] + b1r[1];
        float gg = gbuf[(1 * 32 + eb) * 16 + 8 + eni] + b1r[2];
        float go = gbuf[(1 * 32 + eb) * 16 + 12 + eni] + b1r[3];
        c1r = sigmf(gf) * c1r + sigmf(gi) * tanhf(gg);
        hstage[1 * 128 + tid] = (_Float16)(sigmf(go) * tanhf(c1r));
      }
      if (tau >= 2) {  // layer 2
        float gi = gbuf[(2 * 32 + eb) * 16 + eni] + b2r[0];
        float gf = gbuf[(2 * 32 + eb) * 16 + 4 + eni] + b2r[1];
        float gg = gbuf[(2 * 32 + eb) * 16 + 8 + eni] + b2r[2];
        float go = gbuf[(2 * 32 + eb) * 16 + 12 + eni] + b2r[3];
        c2r = sigmf(gf) * c2r + sigmf(gi) * tanhf(gg);
        float h = sigmf(go) * tanhf(c2r);
        _Float16 hb = (_Float16)h;
        hstage[2 * 128 + tid] = hb;
        int t2 = tau - 2;
        h2all[(size_t)(t2 * BB + eb) * HH + en] = hb;
        concat[(size_t)(t2 * BB + eb) * 2048 + 1024 + en] = hb;
      }
    }
    __syncthreads();   // hstage visible in LDS
    // pack phase: 96 threads emit one 8B agent-scope (sc1) store each — no wbl2
    {
      bool act = (tid < 96) &&
                 ((pk_l == 0) ? (tau < 128)
                  : (pk_l == 1) ? (tau >= 1 && tau < 129) : (tau >= 2));
      if (act) {
        unsigned long long v = *(const unsigned long long*)&hstage[pk_l * 128 + pk_r * 4];
        __hip_atomic_store(
            (unsigned long long*)(hfrag + (size_t)(pk_l * 2 + p) * 32768 + pk_idx), v,
            __ATOMIC_RELAXED, __HIP_MEMORY_SCOPE_AGENT);
      }
      asm volatile("s_waitcnt vmcnt(0)" ::: "memory");   // own sc1 stores at LLC
    }
    __syncthreads();   // all pack stores complete before flag
    if (tid == 0)
      __hip_atomic_store(&arrive[w * 32], (unsigned)(tau + 1), __ATOMIC_RELAXED,
                         __HIP_MEMORY_SCOPE_AGENT);
    if (tau < 129) {   // last tick: no one consumes, skip the wait
      if (tid < 64) {
        for (;;) {
          bool ok = true;
#pragma unroll
          for (int j = 0; j < 4; ++j) {
            unsigned v = __hip_atomic_load(&arrive[(tid * 4 + j) * 32], __ATOMIC_RELAXED,
                                           __HIP_MEMORY_SCOPE_AGENT);
            ok &= (v >= (unsigned)(tau + 1));
          }
          if (__all(ok)) break;
          __builtin_amdgcn_s_sleep(1);
        }
        __builtin_amdgcn_fence(__ATOMIC_ACQUIRE, "agent");  // inv L1/L2, no writeback
      }
      __syncthreads();
    }
  }
}

// ---------------- fused scores+softmax+weighted-context per (t,b) ----------------
__global__ __launch_bounds__(256) void k_attn(const _Float16* __restrict__ target,
                                              const _Float16* __restrict__ encb,
                                              _Float16* __restrict__ concat) {
  __shared__ float sc[64];
  __shared__ float att[64];
  int m = blockIdx.x, b = m & 31;
  int tid = threadIdx.x, lane = tid & 63, wv = tid >> 6;
  const h16x8* tp = (const h16x8*)(target + (size_t)m * EE + lane * 16);
  h16x8 tg0 = tp[0], tg1 = tp[1];
  for (int si = 0; si < 16; ++si) {
    int s = wv * 16 + si;
    const h16x8* ep = (const h16x8*)(encb + ((size_t)s * BB + b) * EE + lane * 16);
    h16x8 e0 = ep[0], e1 = ep[1];
    float a = 0.f;
#pragma unroll
    for (int j = 0; j < 8; ++j) a += (float)e0[j] * (float)tg0[j];
#pragma unroll
    for (int j = 0; j < 8; ++j) a += (float)e1[j] * (float)tg1[j];
#pragma unroll
    for (int off = 32; off >= 1; off >>= 1) a += __shfl_xor(a, off);
    if (lane == 0) sc[s] = a;
  }
  __syncthreads();
  if (wv == 0) {
    float v = sc[lane], mx = v;
#pragma unroll
    for (int off = 32; off >= 1; off >>= 1) mx = fmaxf(mx, __shfl_xor(mx, off));
    float e = expf(v - mx), sm = e;
#pragma unroll
    for (int off = 32; off >= 1; off >>= 1) sm += __shfl_xor(sm, off);
    att[lane] = e / sm;
  }
  __syncthreads();
  int e4 = tid * 4;
  float a0 = 0, a1 = 0, a2 = 0, a3 = 0;
  for (int s = 0; s < 64; ++s) {
    float wgt = att[s];
    h16x4 ev = *(const h16x4*)(encb + ((size_t)s * BB + b) * EE + e4);
    a0 += wgt * (float)ev[0]; a1 += wgt * (float)ev[1];
    a2 += wgt * (float)ev[2]; a3 += wgt * (float)ev[3];
  }
  h16x4 o; o[0] = (_Float16)a0; o[1] = (_Float16)a1; o[2] = (_Float16)a2; o[3] = (_Float16)a3;
  *(h16x4*)(concat + (size_t)m * 2048 + e4) = o;
}

// ---------------- host ----------------
extern "C" void kernel_launch(void* const* d_in, const int* in_sizes, int n_in,
                              void* d_out, int out_size, void* d_ws, size_t ws_size,
                              hipStream_t stream) {
  const int* tokens = (const int*)d_in[0];
  const float* embW = (const float*)d_in[1];
  const float* Wih = (const float*)d_in[2];
  const float* Whh = (const float*)d_in[3];
  const float* bih = (const float*)d_in[4];
  const float* bhh = (const float*)d_in[5];
  const float* Win = (const float*)d_in[6];
  const float* Wout = (const float*)d_in[7];
  const float* finalb = (const float*)d_in[8];
  const float* enc = (const float*)d_in[9];
  const float* h0 = (const float*)d_in[10];
  const float* c0 = (const float*)d_in[11];
  (void)in_sizes; (void)n_in; (void)out_size;
  if (ws_size < WS_NEEDED) return;

  char* ws = (char*)d_ws;
  unsigned* sync = (unsigned*)(ws + OFF_SYNC);
  _Float16* hfrag = (_Float16*)(ws + OFF_HFRAG);
  _Float16* emb = (_Float16*)(ws + OFF_EMB);
  _Float16* X0bf = (_Float16*)(ws + OFF_X0);
  _Float16* Wih0b = (_Float16*)(ws + OFF_WIH0);
  _Float16* Wp4 = (_Float16*)(ws + OFF_WP4);
  _Float16* Wp0 = (_Float16*)(ws + OFF_WP0);
  _Float16* embWb = (_Float16*)(ws + OFF_EMBW);
  _Float16* Winb = (_Float16*)(ws + OFF_WIN);
  _Float16* Woutb = (_Float16*)(ws + OFF_WOUT);
  _Float16* encb = (_Float16*)(ws + OFF_ENC);
  _Float16* h2all = (_Float16*)(ws + OFF_H2ALL);
  _Float16* concat = (_Float16*)(ws + OFF_CONCAT);
  _Float16* target = (_Float16*)(ws + OFF_TARGET);
  _Float16* ht = (_Float16*)(ws + OFF_HT);

  const unsigned LDSB = 155648;  // 128KB weights + 18KB redbuf + 6KB gbuf
  static int lds_set = 0;
  if (!lds_set) {
    hipFuncSetAttribute((const void*)k_recur, hipFuncAttributeMaxDynamicSharedMemorySize,
                        (int)LDSB);
    lds_set = 1;   // attribute is sticky on the function; setting once is enough
  }

  // prep: converts / packs / init
  k_conv<<<4096, 256, 0, stream>>>(embW, embWb, VV * EE / 4);
  k_conv<<<1024, 256, 0, stream>>>(Wih, Wih0b, G4 * EE / 4);       // layer-0 W_ih
  k_conv<<<512, 256, 0, stream>>>(Win, Winb, EE * EE / 4);
  k_conv<<<512, 256, 0, stream>>>(Wout, Woutb, EE * 2048 / 4);
  k_conv<<<512, 256, 0, stream>>>(enc, encb, 64 * BB * EE / 4);
  k_gather<<<NROWS, 256, 0, stream>>>(tokens, embW, emb);
  k_packw4<<<8192, 256, 0, stream>>>(Wih, Whh, Wp4);
  k_packw0<<<4096, 256, 0, stream>>>(Whh, Wp0);
  k_init<<<384, 256, 0, stream>>>(h0, hfrag, sync);

  // X0 = emb @ Wih0^T + b_ih0 + b_hh0   -> f16 [4096,4096]
  k_gemm<3><<<32 * 32, 256, 0, stream>>>(emb, Wih0b, X0bf, NROWS, G4, EE, bih, bhh);

  // recurrence: REGULAR launch (graph-capturable); co-residency structural
  k_recur<<<256, 512, LDSB, stream>>>(Wp4, Wp0, X0bf, hfrag, h2all, concat,
                                      bih, bhh, c0, sync);

  // attention chain
  k_gemm<1><<<32 * 8, 256, 0, stream>>>(h2all, Winb, target, NROWS, EE, EE, nullptr, nullptr);
  k_attn<<<NROWS, 256, 0, stream>>>(target, encb, concat);
  k_gemm<2><<<32 * 8, 256, 0, stream>>>(concat, Woutb, ht, NROWS, EE, 2048, nullptr, nullptr);

  // logits = ht @ embW^T + final_b  -> f32 d_out
  k_gemm<0><<<32 * 250, 256, 0, stream>>>(ht, embWb, d_out, NROWS, VV, EE, finalb, nullptr);
}